// Round 5
// baseline (71.656 us; speedup 1.0000x reference)
//
#include <hip/hip_runtime.h>

typedef __attribute__((ext_vector_type(8))) __bf16 bf16x8;
typedef __attribute__((ext_vector_type(4))) float f32x4;

#define M_ 256
#define N_ 4096
#define K_ 4096
#define SPLITK 4
#define KC (K_ / SPLITK)   // 1024
#define BM 128
#define BN 128
#define BK 64
#define KSTEPS (KC / BK)   // 16
#define NCH 48             // 1KB chunks per K-step tile: A_hi 16 | A_lo 16 | B 16
#define LDSBUF 49152       // NCH KB

// Tiled operand layout: 1KB tile = 16 rows x 32 k, lane-major:
//   tile(rt, kt) at ushort offset (rt*128 + kt)*512; within: lane=(row&15)+16*((k>>3)&3), elem=k&7
// -> every global_load_lds reads contiguous 1KB (lane*16B), zero scatter.

// ---------- helpers ----------

__device__ __forceinline__ unsigned short f2bf(float f) {
  unsigned int u = __builtin_bit_cast(unsigned int, f);
  u += 0x7fffu + ((u >> 16) & 1u);
  return (unsigned short)(u >> 16);
}

__device__ __forceinline__ void async16(const void* g, void* l) {
  __builtin_amdgcn_global_load_lds(
      (const __attribute__((address_space(1))) unsigned int*)g,
      (__attribute__((address_space(3))) unsigned int*)l, 16, 0, 0);
}

__device__ __forceinline__ float lsq1(float y, float a, float s) {
  float yc = fminf(fmaxf(y, -a), a);
  return rintf(yc / s) * s;
}

// ---------- K1: lattice-quantize weights -> z_mod (bf16 bits, TILED layout) ----------
// z dot: f32, UNFUSED mul+add, sequential ascending — bit-matches XLA:CPU ref.
// DO NOT TOUCH the arithmetic (verified absmax 0.0117); only the output
// addressing is tiled.

__global__ __launch_bounds__(256) void k_quant(const float* __restrict__ W,
                                               const float* __restrict__ theta,
                                               const float* __restrict__ Ginv,
                                               unsigned short* __restrict__ zq,
                                               int kTheta) {
  __shared__ float Gi[64];
  const int tid = threadIdx.x;
  if (tid < 64) Gi[tid] = Ginv[tid];
  __syncthreads();
  const int bid = blockIdx.x * 256 + tid;     // 0 .. N_*K_/8-1
  const int o = bid >> 9;                     // row
  const int kb = bid & 511;                   // 8-elt block within row
  const float4* wp = (const float4*)(W + (size_t)bid * 8);
  const float4 w0 = wp[0], w1 = wp[1];
  float sc = 0.f;
  for (int t = 0; t < kTheta; ++t) sc += theta[o * kTheta + t];
  sc /= (float)kTheta;
  const float wsv[8] = {w0.x * sc, w0.y * sc, w0.z * sc, w0.w * sc,
                        w1.x * sc, w1.y * sc, w1.z * sc, w1.w * sc};
  unsigned int packed[4] = {0u, 0u, 0u, 0u};
  const unsigned long long lut = 0x3F800000BF80C000ull;  // idx 0..3 -> -2,-1,0,+1 (bf16)
#pragma unroll
  for (int i = 0; i < 8; ++i) {
    float t = 0.f;
#pragma unroll
    for (int j = 0; j < 8; ++j)
      t = __fadd_rn(t, __fmul_rn(wsv[j], Gi[j * 8 + i]));  // unfused, sequential
    const int zi = (int)rintf(t);
    const int idx = (zi + 2) & 3;
    const unsigned int h = (unsigned int)((lut >> (idx * 16)) & 0xFFFFull);
    packed[i >> 1] |= h << ((i & 1) * 16);
  }
  // tiled write: tile(rt=o>>4, kt=kb>>2), lane=(o&15)+16*(kb&3)
  const size_t dst = ((size_t)((o >> 4) * 128 + (kb >> 2)) << 9) +
                     (size_t)(((o & 15) + ((kb & 3) << 4)) << 3);
  *(uint4*)(zq + dst) = make_uint4(packed[0], packed[1], packed[2], packed[3]);
}

// ---------- K2: xg = x_blocks @ G^T -> bf16 hi/lo (TILED layout) ----------

__global__ __launch_bounds__(256) void k_xg(const float* __restrict__ x,
                                            const float* __restrict__ G,
                                            unsigned short* __restrict__ hi,
                                            unsigned short* __restrict__ lo) {
  __shared__ float Gs[64];
  const int tid = threadIdx.x;
  if (tid < 64) Gs[tid] = G[tid];
  __syncthreads();
  const int bid = blockIdx.x * 256 + tid;     // 0 .. M_*K_/8-1
  const int m = bid >> 9;
  const int kb = bid & 511;
  const float4* xp = (const float4*)(x + (size_t)bid * 8);
  const float4 a0 = xp[0], a1 = xp[1];
  float xv[8] = {a0.x, a0.y, a0.z, a0.w, a1.x, a1.y, a1.z, a1.w};
  unsigned int ph[4] = {0u, 0u, 0u, 0u}, pl[4] = {0u, 0u, 0u, 0u};
#pragma unroll
  for (int i = 0; i < 8; ++i) {
    float t = 0.f;
#pragma unroll
    for (int j = 0; j < 8; ++j) t = fmaf(xv[j], Gs[i * 8 + j], t);
    const unsigned short hb = f2bf(t);
    const float hf = __builtin_bit_cast(float, (unsigned int)hb << 16);
    const unsigned short lb = f2bf(t - hf);
    ph[i >> 1] |= ((unsigned int)hb) << ((i & 1) * 16);
    pl[i >> 1] |= ((unsigned int)lb) << ((i & 1) * 16);
  }
  const size_t dst = ((size_t)((m >> 4) * 128 + (kb >> 2)) << 9) +
                     (size_t)(((m & 15) + ((kb & 3) << 4)) << 3);
  *(uint4*)(hi + dst) = make_uint4(ph[0], ph[1], ph[2], ph[3]);
  *(uint4*)(lo + dst) = make_uint4(pl[0], pl[1], pl[2], pl[3]);
}

// ---------- K3: split-K GEMM, y_part = xg_hi@z^T + xg_lo@z^T ----------
// 512 threads = 8 waves (4m x 2n, each wave 32x64 out), tile 128x128, BK=64,
// double-buffered 2-phase loop, contiguous-1KB global_load_lds staging.
// XCD decode: b&7 = (mt, sk) -> all blocks on one XCD share the same 512KB
// A-slice (L2-resident). Per-output MFMA sequence identical to verified r3.

__global__ __launch_bounds__(512, 2) void k_gemm(const unsigned short* __restrict__ xgh,
                                                 const unsigned short* __restrict__ xgl,
                                                 const unsigned short* __restrict__ z,
                                                 float* __restrict__ part) {
  __shared__ uint4 smem4[2 * LDSBUF / 16];  // 96KB double buffer
  char* smem = (char*)smem4;

  const int tid = threadIdx.x;
  const int lane = tid & 63, wave = tid >> 6;
  const int wr = wave >> 1, wc = wave & 1;   // wave grid 4 x 2
  const int b = blockIdx.x;
  const int mt = b & 1;
  const int sk = (b >> 1) & 3;
  const int nt = b >> 3;                     // 0..31
  const int k0t = sk * (KC / 32);            // base k-tile
  const int rowa16 = mt * (BM / 16);
  const int rowb16 = nt * (BN / 16);
  const int lrow = lane & 15, lkg = lane >> 4;

  // 48 chunks: c 0..15 = A_hi (sm=c>>1, kk=c&1), 16..31 = A_lo, 32..47 = B
  const unsigned short* src[6];
  unsigned int ldso[6];
#pragma unroll
  for (int ci = 0; ci < 6; ++ci) {
    const int c = wave * 6 + ci;
    const unsigned short* P;
    int rt;
    if (c < 16)      { P = xgh; rt = rowa16 + (c >> 1); }
    else if (c < 32) { P = xgl; rt = rowa16 + ((c - 16) >> 1); }
    else             { P = z;   rt = rowb16 + ((c - 32) >> 1); }
    src[ci] = P + (((size_t)(rt * 128 + k0t + (c & 1))) << 9) + lane * 8;
    ldso[ci] = (unsigned int)c * 1024u;
  }

  f32x4 acc[2][4] = {};

  // prologue: stage tile 0 into buffer 0
#pragma unroll
  for (int ci = 0; ci < 6; ++ci) async16(src[ci], smem + ldso[ci]);
  __syncthreads();

  for (int ks = 0; ks < KSTEPS; ++ks) {
    const int cur = (ks & 1) * LDSBUF;
    const int nxt = LDSBUF - cur;
    if (ks + 1 < KSTEPS) {
#pragma unroll
      for (int ci = 0; ci < 6; ++ci)
        async16(src[ci] + (size_t)(ks + 1) * 1024, smem + nxt + ldso[ci]);
    }

#pragma unroll
    for (int kk = 0; kk < 2; ++kk) {
      bf16x8 bfr[4], ah[2], al[2];
#pragma unroll
      for (int nf = 0; nf < 4; ++nf)
        bfr[nf] = *(const bf16x8*)(smem + cur + (32 + (wc * 4 + nf) * 2 + kk) * 1024 + lane * 16);
#pragma unroll
      for (int mf = 0; mf < 2; ++mf) {
        ah[mf] = *(const bf16x8*)(smem + cur + ((wr * 2 + mf) * 2 + kk) * 1024 + lane * 16);
        al[mf] = *(const bf16x8*)(smem + cur + (16 + (wr * 2 + mf) * 2 + kk) * 1024 + lane * 16);
      }
#pragma unroll
      for (int mf = 0; mf < 2; ++mf)
#pragma unroll
        for (int nf = 0; nf < 4; ++nf) {
          acc[mf][nf] = __builtin_amdgcn_mfma_f32_16x16x32_bf16(ah[mf], bfr[nf], acc[mf][nf], 0, 0, 0);
          acc[mf][nf] = __builtin_amdgcn_mfma_f32_16x16x32_bf16(al[mf], bfr[nf], acc[mf][nf], 0, 0, 0);
        }
    }
    __syncthreads();  // drains the stage issued above, after compute
  }

  // C/D layout (m89-verified): col = lane&15, row = (lane>>4)*4 + reg
  float* pb = part + (size_t)sk * (M_ * N_);
  const int row_a = mt * BM, row_b = nt * BN;
#pragma unroll
  for (int mf = 0; mf < 2; ++mf)
#pragma unroll
    for (int nf = 0; nf < 4; ++nf)
#pragma unroll
      for (int r = 0; r < 4; ++r) {
        const int m = row_a + wr * 32 + mf * 16 + lkg * 4 + r;
        const int n = row_b + wc * 64 + nf * 16 + lrow;
        pb[(size_t)m * N_ + n] = acc[mf][nf][r];
      }
}

// ---------- K4: reduce split-K partials + bias + LSQ epilogue ----------

__global__ __launch_bounds__(256) void k_epi(const float* __restrict__ part,
                                             const float* __restrict__ bias,
                                             const float* __restrict__ alpha,
                                             float* __restrict__ out) {
  const int i4 = blockIdx.x * 256 + threadIdx.x;  // over M_*N_/4
  const size_t off = (size_t)i4 * 4;
  const float4 p0 = *(const float4*)(part + off);
  const float4 p1 = *(const float4*)(part + (size_t)1 * M_ * N_ + off);
  const float4 p2 = *(const float4*)(part + (size_t)2 * M_ * N_ + off);
  const float4 p3 = *(const float4*)(part + (size_t)3 * M_ * N_ + off);
  const int n = (int)(off & (N_ - 1));
  const float4 bv = *(const float4*)(bias + n);
  const float a = fmaxf(alpha[0], 0.f) + 1e-8f;
  const float s = a / 127.0f;
  float4 o;
  o.x = lsq1(((p0.x + p1.x) + p2.x) + p3.x + bv.x, a, s);
  o.y = lsq1(((p0.y + p1.y) + p2.y) + p3.y + bv.y, a, s);
  o.z = lsq1(((p0.z + p1.z) + p2.z) + p3.z + bv.z, a, s);
  o.w = lsq1(((p0.w + p1.w) + p2.w) + p3.w + bv.w, a, s);
  *(float4*)(out + off) = o;
}

// ---------- launch ----------

extern "C" void kernel_launch(void* const* d_in, const int* in_sizes, int n_in,
                              void* d_out, int out_size, void* d_ws, size_t ws_size,
                              hipStream_t stream) {
  const float* x     = (const float*)d_in[0];
  const float* W     = (const float*)d_in[1];
  const float* bias  = (const float*)d_in[2];
  const float* theta = (const float*)d_in[3];
  const float* alpha = (const float*)d_in[4];
  const float* G     = (const float*)d_in[5];
  const float* Ginv  = (const float*)d_in[6];
  float* out = (float*)d_out;

  const int O = in_sizes[2];           // 4096
  const int kTheta = in_sizes[3] / O;  // 1

  // ws layout: z bf16 tiled 32MB | xg_hi 2MB | xg_lo 2MB | partials [S][M][N] 16MB
  char* ws = (char*)d_ws;
  unsigned short* zq  = (unsigned short*)ws;
  unsigned short* xgh = (unsigned short*)(ws + 33554432);
  unsigned short* xgl = (unsigned short*)(ws + 35651584);
  float* part = (float*)(ws + 37748736);
  if (ws_size < 54525952) return;  // guard: need 52MB scratch

  k_quant<<<(N_ * K_ / 8) / 256, 256, 0, stream>>>(W, theta, Ginv, zq, kTheta);
  k_xg<<<(M_ * K_ / 8) / 256, 256, 0, stream>>>(x, G, xgh, xgl);
  k_gemm<<<2 * 4 * 32, 512, 0, stream>>>(xgh, xgl, zq, part);
  k_epi<<<(M_ * N_ / 4) / 256, 256, 0, stream>>>(part, bias, alpha, out);
}

// Round 6
// 52.070 us; speedup vs baseline: 1.3762x; 1.3762x over previous
//
#include <hip/hip_runtime.h>

typedef __attribute__((ext_vector_type(8))) __bf16 bf16x8;
typedef __attribute__((ext_vector_type(4))) float f32x4;

#define M_ 256
#define N_ 4096
#define K_ 4096
#define SPLITK 4
#define KC (K_ / SPLITK)   // 1024
#define BM 128
#define BN 128
#define BK 64
#define KSTEPS (KC / BK)   // 16
#define NCH 48             // 1KB chunks per K-step tile: A_hi 16 | A_lo 16 | B 16
#define LDSBUF 49152       // NCH KB

// Tiled operand layout: 1KB tile = 16 rows x 32 k, lane-major:
//   tile(rt, kt) at ushort offset (rt*128 + kt)*512; within: lane=(row&15)+16*((k>>3)&3), elem=k&7
// -> every global_load_lds reads contiguous 1KB (lane*16B), zero scatter.
// Producers iterate in OUTPUT order (thread = 16B slot) so writes coalesce;
// reads become 16 x 128B line-aligned segments per wave (fine).

// ---------- helpers ----------

__device__ __forceinline__ unsigned short f2bf(float f) {
  unsigned int u = __builtin_bit_cast(unsigned int, f);
  u += 0x7fffu + ((u >> 16) & 1u);
  return (unsigned short)(u >> 16);
}

__device__ __forceinline__ void async16(const void* g, void* l) {
  __builtin_amdgcn_global_load_lds(
      (const __attribute__((address_space(1))) unsigned int*)g,
      (__attribute__((address_space(3))) unsigned int*)l, 16, 0, 0);
}

__device__ __forceinline__ float lsq1(float y, float a, float s) {
  float yc = fminf(fmaxf(y, -a), a);
  return rintf(yc / s) * s;
}

// ---------- K1: lattice-quantize weights -> z_mod (bf16 bits, TILED layout) ----------
// z dot: f32, UNFUSED mul+add, sequential ascending — bit-matches XLA:CPU ref.
// DO NOT TOUCH the arithmetic (verified absmax 0.0117); thread = output slot.

__global__ __launch_bounds__(256) void k_quant(const float* __restrict__ W,
                                               const float* __restrict__ theta,
                                               const float* __restrict__ Ginv,
                                               unsigned short* __restrict__ zq,
                                               int kTheta) {
  __shared__ float Gi[64];
  const int tid = threadIdx.x;
  if (tid < 64) Gi[tid] = Ginv[tid];
  __syncthreads();
  const int s = blockIdx.x * 256 + tid;       // output 16B slot, 0 .. N_*K_/8-1
  const int lane6 = s & 63;
  const int tile = s >> 6;
  const int o  = ((tile >> 7) << 4) + (lane6 & 15);   // row
  const int kb = ((tile & 127) << 2) + (lane6 >> 4);  // 8-elt k-block
  const float4* wp = (const float4*)(W + ((size_t)o << 12) + ((size_t)kb << 3));
  const float4 w0 = wp[0], w1 = wp[1];
  float sc = 0.f;
  for (int t = 0; t < kTheta; ++t) sc += theta[o * kTheta + t];
  sc /= (float)kTheta;
  const float wsv[8] = {w0.x * sc, w0.y * sc, w0.z * sc, w0.w * sc,
                        w1.x * sc, w1.y * sc, w1.z * sc, w1.w * sc};
  unsigned int packed[4] = {0u, 0u, 0u, 0u};
  const unsigned long long lut = 0x3F800000BF80C000ull;  // idx 0..3 -> -2,-1,0,+1 (bf16)
#pragma unroll
  for (int i = 0; i < 8; ++i) {
    float t = 0.f;
#pragma unroll
    for (int j = 0; j < 8; ++j)
      t = __fadd_rn(t, __fmul_rn(wsv[j], Gi[j * 8 + i]));  // unfused, sequential
    const int zi = (int)rintf(t);
    const int idx = (zi + 2) & 3;
    const unsigned int h = (unsigned int)((lut >> (idx * 16)) & 0xFFFFull);
    packed[i >> 1] |= h << ((i & 1) * 16);
  }
  *(uint4*)(zq + ((size_t)s << 3)) = make_uint4(packed[0], packed[1], packed[2], packed[3]);
}

// ---------- K2: xg = x_blocks @ G^T -> bf16 hi/lo (TILED layout) ----------

__global__ __launch_bounds__(256) void k_xg(const float* __restrict__ x,
                                            const float* __restrict__ G,
                                            unsigned short* __restrict__ hi,
                                            unsigned short* __restrict__ lo) {
  __shared__ float Gs[64];
  const int tid = threadIdx.x;
  if (tid < 64) Gs[tid] = G[tid];
  __syncthreads();
  const int s = blockIdx.x * 256 + tid;       // output 16B slot, 0 .. M_*K_/8-1
  const int lane6 = s & 63;
  const int tile = s >> 6;
  const int m  = ((tile >> 7) << 4) + (lane6 & 15);
  const int kb = ((tile & 127) << 2) + (lane6 >> 4);
  const float4* xp = (const float4*)(x + ((size_t)m << 12) + ((size_t)kb << 3));
  const float4 a0 = xp[0], a1 = xp[1];
  float xv[8] = {a0.x, a0.y, a0.z, a0.w, a1.x, a1.y, a1.z, a1.w};
  unsigned int ph[4] = {0u, 0u, 0u, 0u}, pl[4] = {0u, 0u, 0u, 0u};
#pragma unroll
  for (int i = 0; i < 8; ++i) {
    float t = 0.f;
#pragma unroll
    for (int j = 0; j < 8; ++j) t = fmaf(xv[j], Gs[i * 8 + j], t);
    const unsigned short hb = f2bf(t);
    const float hf = __builtin_bit_cast(float, (unsigned int)hb << 16);
    const unsigned short lb = f2bf(t - hf);
    ph[i >> 1] |= ((unsigned int)hb) << ((i & 1) * 16);
    pl[i >> 1] |= ((unsigned int)lb) << ((i & 1) * 16);
  }
  *(uint4*)(hi + ((size_t)s << 3)) = make_uint4(ph[0], ph[1], ph[2], ph[3]);
  *(uint4*)(lo + ((size_t)s << 3)) = make_uint4(pl[0], pl[1], pl[2], pl[3]);
}

// ---------- K3: split-K GEMM, y_part = xg_hi@z^T + xg_lo@z^T ----------
// 512 threads = 8 waves (4m x 2n, each wave 32x64 out), tile 128x128, BK=64,
// double-buffered 2-phase loop, contiguous-1KB global_load_lds staging.
// XCD decode: b&7 = (mt, sk) -> all blocks on one XCD share the same 512KB
// A-slice (L2-resident). Per-output MFMA sequence identical to verified r3.

__global__ __launch_bounds__(512, 2) void k_gemm(const unsigned short* __restrict__ xgh,
                                                 const unsigned short* __restrict__ xgl,
                                                 const unsigned short* __restrict__ z,
                                                 float* __restrict__ part) {
  __shared__ uint4 smem4[2 * LDSBUF / 16];  // 96KB double buffer
  char* smem = (char*)smem4;

  const int tid = threadIdx.x;
  const int lane = tid & 63, wave = tid >> 6;
  const int wr = wave >> 1, wc = wave & 1;   // wave grid 4 x 2
  const int b = blockIdx.x;
  const int mt = b & 1;
  const int sk = (b >> 1) & 3;
  const int nt = b >> 3;                     // 0..31
  const int k0t = sk * (KC / 32);            // base k-tile
  const int rowa16 = mt * (BM / 16);
  const int rowb16 = nt * (BN / 16);
  const int lrow = lane & 15, lkg = lane >> 4;

  // 48 chunks: c 0..15 = A_hi (sm=c>>1, kk=c&1), 16..31 = A_lo, 32..47 = B
  const unsigned short* src[6];
  unsigned int ldso[6];
#pragma unroll
  for (int ci = 0; ci < 6; ++ci) {
    const int c = wave * 6 + ci;
    const unsigned short* P;
    int rt;
    if (c < 16)      { P = xgh; rt = rowa16 + (c >> 1); }
    else if (c < 32) { P = xgl; rt = rowa16 + ((c - 16) >> 1); }
    else             { P = z;   rt = rowb16 + ((c - 32) >> 1); }
    src[ci] = P + (((size_t)(rt * 128 + k0t + (c & 1))) << 9) + lane * 8;
    ldso[ci] = (unsigned int)c * 1024u;
  }

  f32x4 acc[2][4] = {};

  // prologue: stage tile 0 into buffer 0
#pragma unroll
  for (int ci = 0; ci < 6; ++ci) async16(src[ci], smem + ldso[ci]);
  __syncthreads();

  for (int ks = 0; ks < KSTEPS; ++ks) {
    const int cur = (ks & 1) * LDSBUF;
    const int nxt = LDSBUF - cur;
    if (ks + 1 < KSTEPS) {
#pragma unroll
      for (int ci = 0; ci < 6; ++ci)
        async16(src[ci] + (size_t)(ks + 1) * 1024, smem + nxt + ldso[ci]);
    }

#pragma unroll
    for (int kk = 0; kk < 2; ++kk) {
      bf16x8 bfr[4], ah[2], al[2];
#pragma unroll
      for (int nf = 0; nf < 4; ++nf)
        bfr[nf] = *(const bf16x8*)(smem + cur + (32 + (wc * 4 + nf) * 2 + kk) * 1024 + lane * 16);
#pragma unroll
      for (int mf = 0; mf < 2; ++mf) {
        ah[mf] = *(const bf16x8*)(smem + cur + ((wr * 2 + mf) * 2 + kk) * 1024 + lane * 16);
        al[mf] = *(const bf16x8*)(smem + cur + (16 + (wr * 2 + mf) * 2 + kk) * 1024 + lane * 16);
      }
#pragma unroll
      for (int mf = 0; mf < 2; ++mf)
#pragma unroll
        for (int nf = 0; nf < 4; ++nf) {
          acc[mf][nf] = __builtin_amdgcn_mfma_f32_16x16x32_bf16(ah[mf], bfr[nf], acc[mf][nf], 0, 0, 0);
          acc[mf][nf] = __builtin_amdgcn_mfma_f32_16x16x32_bf16(al[mf], bfr[nf], acc[mf][nf], 0, 0, 0);
        }
    }
    __syncthreads();  // drains the stage issued above, after compute
  }

  // C/D layout (m89-verified): col = lane&15, row = (lane>>4)*4 + reg
  float* pb = part + (size_t)sk * (M_ * N_);
  const int row_a = mt * BM, row_b = nt * BN;
#pragma unroll
  for (int mf = 0; mf < 2; ++mf)
#pragma unroll
    for (int nf = 0; nf < 4; ++nf)
#pragma unroll
      for (int r = 0; r < 4; ++r) {
        const int m = row_a + wr * 32 + mf * 16 + lkg * 4 + r;
        const int n = row_b + wc * 64 + nf * 16 + lrow;
        pb[(size_t)m * N_ + n] = acc[mf][nf][r];
      }
}

// ---------- K4: reduce split-K partials + bias + LSQ epilogue ----------

__global__ __launch_bounds__(256) void k_epi(const float* __restrict__ part,
                                             const float* __restrict__ bias,
                                             const float* __restrict__ alpha,
                                             float* __restrict__ out) {
  const int i4 = blockIdx.x * 256 + threadIdx.x;  // over M_*N_/4
  const size_t off = (size_t)i4 * 4;
  const float4 p0 = *(const float4*)(part + off);
  const float4 p1 = *(const float4*)(part + (size_t)1 * M_ * N_ + off);
  const float4 p2 = *(const float4*)(part + (size_t)2 * M_ * N_ + off);
  const float4 p3 = *(const float4*)(part + (size_t)3 * M_ * N_ + off);
  const int n = (int)(off & (N_ - 1));
  const float4 bv = *(const float4*)(bias + n);
  const float a = fmaxf(alpha[0], 0.f) + 1e-8f;
  const float s = a / 127.0f;
  float4 o;
  o.x = lsq1(((p0.x + p1.x) + p2.x) + p3.x + bv.x, a, s);
  o.y = lsq1(((p0.y + p1.y) + p2.y) + p3.y + bv.y, a, s);
  o.z = lsq1(((p0.z + p1.z) + p2.z) + p3.z + bv.z, a, s);
  o.w = lsq1(((p0.w + p1.w) + p2.w) + p3.w + bv.w, a, s);
  *(float4*)(out + off) = o;
}

// ---------- launch ----------

extern "C" void kernel_launch(void* const* d_in, const int* in_sizes, int n_in,
                              void* d_out, int out_size, void* d_ws, size_t ws_size,
                              hipStream_t stream) {
  const float* x     = (const float*)d_in[0];
  const float* W     = (const float*)d_in[1];
  const float* bias  = (const float*)d_in[2];
  const float* theta = (const float*)d_in[3];
  const float* alpha = (const float*)d_in[4];
  const float* G     = (const float*)d_in[5];
  const float* Ginv  = (const float*)d_in[6];
  float* out = (float*)d_out;

  const int O = in_sizes[2];           // 4096
  const int kTheta = in_sizes[3] / O;  // 1

  // ws layout: z bf16 tiled 32MB | xg_hi 2MB | xg_lo 2MB | partials [S][M][N] 16MB
  char* ws = (char*)d_ws;
  unsigned short* zq  = (unsigned short*)ws;
  unsigned short* xgh = (unsigned short*)(ws + 33554432);
  unsigned short* xgl = (unsigned short*)(ws + 35651584);
  float* part = (float*)(ws + 37748736);
  if (ws_size < 54525952) return;  // guard: need 52MB scratch

  k_quant<<<(N_ * K_ / 8) / 256, 256, 0, stream>>>(W, theta, Ginv, zq, kTheta);
  k_xg<<<(M_ * K_ / 8) / 256, 256, 0, stream>>>(x, G, xgh, xgl);
  k_gemm<<<2 * 4 * 32, 512, 0, stream>>>(xgh, xgl, zq, part);
  k_epi<<<(M_ * N_ / 4) / 256, 256, 0, stream>>>(part, bias, alpha, out);
}